// Round 7
// baseline (9517.857 us; speedup 1.0000x reference)
//
#include <hip/hip_runtime.h>
#include <hip/hip_bf16.h>
#include <math.h>

// ConvLSTMClassifier on MI355X — 8-steps-per-launch, c-in-registers MFMA.
// 16-wave blocks: 8 ch-slices x 2 M-groups (anti-spill: ~110 live regs/thread).
// gates[b,w,n] = bias[n] + sum_kx x[b,t,w+kx-1]*pxw[kx,n]
//              + sum_kx sum_ic h[b,w+kx-1,ic]*Bp[kx,n,ic],  n = g*128+ch.
// Fixed-origin indexing: slab row j <-> w = w0-9+j, output row m <-> w0-8+m.
// c[w] stays in its lane's register across all 8 fused steps. Validity
// window [s+1, 142-s]; invalid rows write h=0 so slabs stay clean.
// Group A (waves 0-7): m-frags 0-4; group B (waves 8-15): m-frags 5-8.
// grid = (4 wtiles, 64 b) = 256 blocks, 1024 thr.

constexpr int kB  = 64;
constexpr int kCH = 128;
constexpr int kH  = 128;
constexpr int kW  = 512;
constexpr int kNC = 10;
constexpr int kT  = 8;     // fused steps per launch
constexpr int ROWS = 146;  // slab rows

typedef __attribute__((ext_vector_type(8))) short short8v;
typedef __attribute__((ext_vector_type(4))) float float4v;

__device__ __forceinline__ float fsig(float v) {
    return 1.0f / (1.0f + __expf(-v));
}
__device__ __forceinline__ float ftanh(float v) {
    float e = __expf(2.0f * v);
    return 1.0f - 2.0f / (e + 1.0f);
}

// ---------------------------------------------------------------------------
// Weight pack: Bp[kx][oc][ic] bf16, pxw[kx][oc] f32, pb[oc] f32.
// Also zeroes the pooled accumulator (ws is poisoned before timing).
// ---------------------------------------------------------------------------
__global__ __launch_bounds__(256) void pack_weights(
    const float* __restrict__ conv_w,  // [512][129][3][3]
    const float* __restrict__ conv_b,  // [512]
    short* __restrict__ Bp,            // [3][512][128]
    float* __restrict__ pxw,           // [3][512]
    float* __restrict__ pb,            // [512]
    float* __restrict__ pooled)        // [64][128]
{
    int idx = blockIdx.x * 256 + threadIdx.x;
    if (idx < 3 * 512 * 128) {
        int ic = idx & 127;
        int oc = (idx >> 7) & 511;
        int kx = idx >> 16;
        float v = conv_w[((oc * 129 + 1 + ic) * 3 + 1) * 3 + kx];
        __hip_bfloat16 hv = __float2bfloat16(v);
        Bp[idx] = *reinterpret_cast<short*>(&hv);
    }
    if (idx < 3 * 512) {
        int oc = idx & 511, kx = idx >> 9;
        pxw[idx] = conv_w[((oc * 129 + 0) * 3 + 1) * 3 + kx];
    }
    if (idx < 512) pb[idx] = conv_b[idx];
    if (idx < kB * kCH) pooled[idx] = 0.0f;
}

// ---------------------------------------------------------------------------
// One fused step for one wave-group (NMF m-frags starting at frag MBASE).
// No barriers inside. Gate-split phases: A = gates i,f ; B = gates g,o.
// ---------------------------------------------------------------------------
template <int NMF, bool FIRST, bool LAST>
__device__ __forceinline__ void step_group(
    int MBASE, int s,
    const short* __restrict__ Sr, short* __restrict__ Sw,
    const short* __restrict__ Bp, const float* __restrict__ xsrow,
    float (&creg)[5][4], float& psum,
    const float (&bia)[4], const float (&wxk)[4][3],
    int w0, int ch, int krow, int ncol,
    size_t gbase, __hip_bfloat16* __restrict__ hOut,
    float* __restrict__ cOut)
{
    float si[5][4];

    // ---- phase A: gates i (g=0), f (g=1) ----
    {
        float4v acc[NMF][2];
#pragma unroll
        for (int mf = 0; mf < NMF; ++mf) {
            acc[mf][0] = float4v{0.f, 0.f, 0.f, 0.f};
            acc[mf][1] = float4v{0.f, 0.f, 0.f, 0.f};
        }
        if (!(FIRST && s == 0)) {
#pragma unroll
            for (int kx = 0; kx < 3; ++kx) {
#pragma unroll
                for (int ks = 0; ks < 4; ++ks) {
                    short8v bf0 = *reinterpret_cast<const short8v*>(
                        Bp + ((kx * 512 + 0 * 128 + ch) * 128 + ks * 32 + krow * 8));
                    short8v bf1 = *reinterpret_cast<const short8v*>(
                        Bp + ((kx * 512 + 1 * 128 + ch) * 128 + ks * 32 + krow * 8));
#pragma unroll
                    for (int mf = 0; mf < NMF; ++mf) {
                        int srow = (MBASE + mf) * 16 + ncol + kx;
                        int slot = (ks * 4 + krow) ^ (srow & 7);
                        short8v afr = *reinterpret_cast<const short8v*>(
                            Sr + srow * 128 + slot * 8);
                        acc[mf][0] = __builtin_amdgcn_mfma_f32_16x16x32_bf16(
                            afr, bf0, acc[mf][0], 0, 0, 0);
                        acc[mf][1] = __builtin_amdgcn_mfma_f32_16x16x32_bf16(
                            afr, bf1, acc[mf][1], 0, 0, 0);
                    }
                }
            }
        }
#pragma unroll
        for (int mf = 0; mf < NMF; ++mf) {
#pragma unroll
            for (int r = 0; r < 4; ++r) {
                int m = (MBASE + mf) * 16 + krow * 4 + r;
                float xm = xsrow[m], xc = xsrow[m + 1], xp = xsrow[m + 2];
                float v0 = acc[mf][0][r] + bia[0] + xm * wxk[0][0] + xc * wxk[0][1] + xp * wxk[0][2];
                float v1 = acc[mf][1][r] + bia[1] + xm * wxk[1][0] + xc * wxk[1][1] + xp * wxk[1][2];
                si[mf][r] = fsig(v0);
                creg[mf][r] = fsig(v1) * creg[mf][r];
            }
        }
    }

    // ---- phase B: gates g (g=2), o (g=3) + state update ----
    {
        float4v acc[NMF][2];
#pragma unroll
        for (int mf = 0; mf < NMF; ++mf) {
            acc[mf][0] = float4v{0.f, 0.f, 0.f, 0.f};
            acc[mf][1] = float4v{0.f, 0.f, 0.f, 0.f};
        }
        if (!(FIRST && s == 0)) {
#pragma unroll
            for (int kx = 0; kx < 3; ++kx) {
#pragma unroll
                for (int ks = 0; ks < 4; ++ks) {
                    short8v bf2 = *reinterpret_cast<const short8v*>(
                        Bp + ((kx * 512 + 2 * 128 + ch) * 128 + ks * 32 + krow * 8));
                    short8v bf3 = *reinterpret_cast<const short8v*>(
                        Bp + ((kx * 512 + 3 * 128 + ch) * 128 + ks * 32 + krow * 8));
#pragma unroll
                    for (int mf = 0; mf < NMF; ++mf) {
                        int srow = (MBASE + mf) * 16 + ncol + kx;
                        int slot = (ks * 4 + krow) ^ (srow & 7);
                        short8v afr = *reinterpret_cast<const short8v*>(
                            Sr + srow * 128 + slot * 8);
                        acc[mf][0] = __builtin_amdgcn_mfma_f32_16x16x32_bf16(
                            afr, bf2, acc[mf][0], 0, 0, 0);
                        acc[mf][1] = __builtin_amdgcn_mfma_f32_16x16x32_bf16(
                            afr, bf3, acc[mf][1], 0, 0, 0);
                    }
                }
            }
        }
#pragma unroll
        for (int mf = 0; mf < NMF; ++mf) {
#pragma unroll
            for (int r = 0; r < 4; ++r) {
                int m = (MBASE + mf) * 16 + krow * 4 + r;
                int w = w0 - 8 + m;
                bool inimg = (w >= 0) && (w < kW);
                bool valid = (m >= s + 1) && (m <= 142 - s) && inimg;
                float xm = xsrow[m], xc = xsrow[m + 1], xp = xsrow[m + 2];
                float v2 = acc[mf][0][r] + bia[2] + xm * wxk[2][0] + xc * wxk[2][1] + xp * wxk[2][2];
                float v3 = acc[mf][1][r] + bia[3] + xm * wxk[3][0] + xc * wxk[3][1] + xp * wxk[3][2];
                float tg = ftanh(v2);
                float so = fsig(v3);
                float cn = creg[mf][r] + si[mf][r] * tg;
                float hn = so * ftanh(cn);
                creg[mf][r] = cn;
                if (s < kT - 1) {
                    __hip_bfloat16 hv = __float2bfloat16(valid ? hn : 0.0f);
                    int j2 = m + 1;  // slab row for this w
                    Sw[j2 * 128 + ((ch >> 3) ^ (j2 & 7)) * 8 + (ch & 7)] =
                        *reinterpret_cast<short*>(&hv);
                } else if (LAST) {
                    if (valid) psum += hn;
                } else if (m >= 8 && m < 136) {
                    size_t gi = gbase + (size_t)w * kCH + ch;
                    hOut[gi] = __float2bfloat16(hn);
                    cOut[gi] = cn;
                }
            }
        }
    }
}

// ---------------------------------------------------------------------------
template <bool FIRST, bool LAST>
__global__ __launch_bounds__(1024) void lstm8(
    const float* __restrict__ x,            // [B][1][H][W]
    const short* __restrict__ Bp,           // [3][512][128]
    const float* __restrict__ pxw,          // [3][512]
    const float* __restrict__ pb,           // [512]
    const __hip_bfloat16* __restrict__ hIn, // [B][W][CH] = h(t0-1)
    __hip_bfloat16* __restrict__ hOut,      // [B][W][CH] = h(t0+7)
    const float* __restrict__ cIn,          // [B][W][CH]
    float* __restrict__ cOut,               // [B][W][CH]
    float* __restrict__ pooled,             // [B][CH]
    int t0)
{
    __shared__ alignas(16) short SA[ROWS * 128];  // swizzled h slab (ping)
    __shared__ alignas(16) short SB[ROWS * 128];  // swizzled h slab (pong)
    __shared__ float xs[kT][ROWS];

    const int tid  = threadIdx.x;
    const int lane = tid & 63;
    const int wave = tid >> 6;          // 0..15
    const int w0   = blockIdx.x * 128;
    const int b    = blockIdx.y;

    const int ncol = lane & 15;
    const int krow = lane >> 4;
    const int chsl = wave & 7;          // ch-slice
    const int mgrp = wave >> 3;         // 0: frags 0-4, 1: frags 5-8
    const int ch   = chsl * 16 + ncol;  // 0..127
    const int nmf  = mgrp ? 4 : 5;
    const int mb   = mgrp ? 5 : 0;      // frag base

    // per-lane constants: bias + x-channel conv weights
    float wxk[4][3], bia[4];
#pragma unroll
    for (int g = 0; g < 4; ++g) {
        bia[g] = pb[g * 128 + ch];
#pragma unroll
        for (int kx = 0; kx < 3; ++kx)
            wxk[g][kx] = pxw[kx * 512 + g * 128 + ch];
    }

    const float* xb = x + ((size_t)b * kH + t0) * kW;
    const size_t gbase = (size_t)b * kW * kCH;

    // ---- staging: h(t0-1) slab (rows w0-9 .. w0+136) + 8 x rows ----
    if (!FIRST) {
        for (int i = tid; i < ROWS * 16; i += 1024) {
            int row = i >> 4, col = i & 15;
            int w = w0 - 9 + row;
            short8v v = {0, 0, 0, 0, 0, 0, 0, 0};
            if (w >= 0 && w < kW)
                v = *reinterpret_cast<const short8v*>(
                    reinterpret_cast<const short*>(hIn) +
                    (gbase + (size_t)w * kCH + col * 8));
            *reinterpret_cast<short8v*>(
                SA + row * 128 + (col ^ (row & 7)) * 8) = v;
        }
    }
    for (int i = tid; i < kT * ROWS; i += 1024) {
        int s8 = i / ROWS, j = i - s8 * ROWS;
        int w = w0 - 9 + j;
        xs[s8][j] = (w >= 0 && w < kW) ? xb[s8 * kW + w] : 0.0f;
    }
    __syncthreads();

    // persistent per-lane cell state (c); guarded unroll keeps indices static
    float creg[5][4];
#pragma unroll
    for (int mf = 0; mf < 5; ++mf) {
        if (mf < nmf) {
#pragma unroll
            for (int r = 0; r < 4; ++r) {
                int m = (mb + mf) * 16 + krow * 4 + r;
                int w = w0 - 8 + m;
                creg[mf][r] = (!FIRST && w >= 0 && w < kW)
                            ? cIn[gbase + (size_t)w * kCH + ch] : 0.0f;
            }
        }
    }
    float psum = 0.0f;

    for (int s = 0; s < kT; ++s) {
        const short* Sr = (s & 1) ? SB : SA;
        short* Sw       = (s & 1) ? SA : SB;
        if (mgrp == 0)
            step_group<5, FIRST, LAST>(0, s, Sr, Sw, Bp, &xs[s][0], creg, psum,
                                       bia, wxk, w0, ch, krow, ncol, gbase,
                                       hOut, cOut);
        else
            step_group<4, FIRST, LAST>(5, s, Sr, Sw, Bp, &xs[s][0], creg, psum,
                                       bia, wxk, w0, ch, krow, ncol, gbase,
                                       hOut, cOut);
        __syncthreads();
    }

    if (LAST) {
        psum += __shfl_xor(psum, 16, 64);
        psum += __shfl_xor(psum, 32, 64);
        if (krow == 0) atomicAdd(&pooled[b * kCH + ch], psum);
    }
}

// ---------------------------------------------------------------------------
// Final FC from pooled sums. grid = B, block = 64.
// ---------------------------------------------------------------------------
__global__ __launch_bounds__(64) void fc_final(
    const float* __restrict__ pooled,  // [B][CH] raw sums over W
    const float* __restrict__ fc_w,    // [NC][CH]
    const float* __restrict__ fc_b,    // [NC]
    float* __restrict__ out)           // [B][NC]
{
    int b = blockIdx.x, nc = threadIdx.x;
    if (nc < kNC) {
        float s = 0.0f;
        for (int k = 0; k < kCH; ++k)
            s = fmaf(pooled[b * kCH + k], fc_w[nc * kCH + k], s);
        out[b * kNC + nc] = fc_b[nc] + s * (1.0f / kW);
    }
}

// ---------------------------------------------------------------------------
extern "C" void kernel_launch(void* const* d_in, const int* in_sizes, int n_in,
                              void* d_out, int out_size, void* d_ws, size_t ws_size,
                              hipStream_t stream) {
    const float* x      = (const float*)d_in[0];
    const float* conv_w = (const float*)d_in[1];
    const float* conv_b = (const float*)d_in[2];
    const float* fc_w   = (const float*)d_in[3];
    const float* fc_b   = (const float*)d_in[4];
    float* out = (float*)d_out;

    const size_t stateN = (size_t)kB * kW * kCH;  // 4,194,304
    float* cA           = (float*)d_ws;
    float* cB           = cA + stateN;
    __hip_bfloat16* hA  = (__hip_bfloat16*)(cB + stateN);
    __hip_bfloat16* hB  = hA + stateN;
    short* Bp           = (short*)(hB + stateN);
    float* pxw          = (float*)(Bp + 3 * 512 * 128);
    float* pb           = pxw + 3 * 512;
    float* pooled       = pb + 512;  // [64][128]

    pack_weights<<<768, 256, 0, stream>>>(conv_w, conv_b, Bp, pxw, pb, pooled);

    dim3 grid(kW / 128, kB);
    dim3 block(1024);
    // launch k handles t = 8k..8k+7. write(k) = k even ? (hB,cB) : (hA,cA);
    // read(k) = write(k-1).
    lstm8<true, false><<<grid, block, 0, stream>>>(
        x, Bp, pxw, pb, hA, hB, cA, cB, pooled, 0);
    for (int k = 1; k < 15; ++k) {
        __hip_bfloat16* hi = (k & 1) ? hB : hA;
        __hip_bfloat16* ho = (k & 1) ? hA : hB;
        float* ci = (k & 1) ? cB : cA;
        float* co = (k & 1) ? cA : cB;
        lstm8<false, false><<<grid, block, 0, stream>>>(
            x, Bp, pxw, pb, hi, ho, ci, co, pooled, 8 * k);
    }
    // k = 15 (odd): reads (hB,cB); outputs pooled only.
    lstm8<false, true><<<grid, block, 0, stream>>>(
        x, Bp, pxw, pb, hB, hA, cB, cA, pooled, 120);

    fc_final<<<kB, 64, 0, stream>>>(pooled, fc_w, fc_b, out);
}

// Round 8
// 5828.585 us; speedup vs baseline: 1.6330x; 1.6330x over previous
//
#include <hip/hip_runtime.h>
#include <hip/hip_bf16.h>
#include <math.h>

// ConvLSTMClassifier on MI355X — 8-step trapezoid fusion, ALL persistent
// per-cell state in LDS (anti-spill: only GEMM accs live in registers).
// gates[b,w,n] = bias[n] + sum_kx x[b,t,w+kx-1]*pxw[kx,n]
//              + sum_kx sum_ic h[b,w+kx-1,ic]*Bp[kx,n,ic],  n = g*128+ch.
// Fixed-origin: slab row j <-> w = w0-9+j, output cell m <-> w = w0-8+m.
// Validity window at step s: m in [s+1, 142-s] (shrinks 1/side/step).
// Single h-slab S, updated in place (GEMM reads -> barrier -> epilogue
// writes; window guarantees step s only reads rows valid at s-1).
// c: f32 in cbuf[tid*37+cell] (owner-thread only). sigma(i): bf16 sibuf.
// Phases per step: A = gates (i,f): si stored, c *= sigma(f);
//                  B = gates (g,o): c += si*tanh(g), h = sigma(o)*tanh(c).
// Block: 512 thr / 8 waves (one 16-ch slice each), M=144 cells, all 512 n.
// grid = (4 wtiles, 64 b) = 256 blocks = 1/CU. 16 launches of 8 steps.

constexpr int kB  = 64;
constexpr int kCH = 128;
constexpr int kH  = 128;
constexpr int kW  = 512;
constexpr int kNC = 10;
constexpr int kT  = 8;     // fused steps per launch
constexpr int ROWS = 146;  // slab rows

typedef __attribute__((ext_vector_type(8))) short short8v;
typedef __attribute__((ext_vector_type(4))) float float4v;

__device__ __forceinline__ float fsig(float v) {
    return 1.0f / (1.0f + __expf(-v));
}
__device__ __forceinline__ float ftanh(float v) {
    float e = __expf(2.0f * v);
    return 1.0f - 2.0f / (e + 1.0f);
}

// ---------------------------------------------------------------------------
// Weight pack: Bp[kx][oc][ic] bf16, pxw[kx][oc] f32, pb[oc] f32.
// Also zeroes the pooled accumulator (ws is poisoned before timing).
// ---------------------------------------------------------------------------
__global__ __launch_bounds__(256) void pack_weights(
    const float* __restrict__ conv_w,  // [512][129][3][3]
    const float* __restrict__ conv_b,  // [512]
    short* __restrict__ Bp,            // [3][512][128]
    float* __restrict__ pxw,           // [3][512]
    float* __restrict__ pb,            // [512]
    float* __restrict__ pooled)        // [64][128]
{
    int idx = blockIdx.x * 256 + threadIdx.x;
    if (idx < 3 * 512 * 128) {
        int ic = idx & 127;
        int oc = (idx >> 7) & 511;
        int kx = idx >> 16;
        float v = conv_w[((oc * 129 + 1 + ic) * 3 + 1) * 3 + kx];
        __hip_bfloat16 hv = __float2bfloat16(v);
        Bp[idx] = *reinterpret_cast<short*>(&hv);
    }
    if (idx < 3 * 512) {
        int oc = idx & 511, kx = idx >> 9;
        pxw[idx] = conv_w[((oc * 129 + 0) * 3 + 1) * 3 + kx];
    }
    if (idx < 512) pb[idx] = conv_b[idx];
    if (idx < kB * kCH) pooled[idx] = 0.0f;
}

// ---------------------------------------------------------------------------
// GEMM for one gate pair (G0,G1): 9 m-frags, K = 3x128 (kx taps x channels).
// ---------------------------------------------------------------------------
template <int G0, int G1>
__device__ __forceinline__ void gemm_pair(
    const short* __restrict__ S, const short* __restrict__ Bp,
    int ch, int krow, int ncol, bool skip, float4v (&acc)[9][2])
{
#pragma unroll
    for (int mf = 0; mf < 9; ++mf) {
        acc[mf][0] = float4v{0.f, 0.f, 0.f, 0.f};
        acc[mf][1] = float4v{0.f, 0.f, 0.f, 0.f};
    }
    if (skip) return;
#pragma unroll
    for (int kx = 0; kx < 3; ++kx) {
#pragma unroll
        for (int ks = 0; ks < 4; ++ks) {
            short8v b0 = *reinterpret_cast<const short8v*>(
                Bp + ((kx * 512 + G0 * 128 + ch) * 128 + ks * 32 + krow * 8));
            short8v b1 = *reinterpret_cast<const short8v*>(
                Bp + ((kx * 512 + G1 * 128 + ch) * 128 + ks * 32 + krow * 8));
#pragma unroll
            for (int mf = 0; mf < 9; ++mf) {
                int srow = mf * 16 + ncol + kx;
                int slot = (ks * 4 + krow) ^ (srow & 7);
                short8v a = *reinterpret_cast<const short8v*>(
                    S + srow * 128 + slot * 8);
                acc[mf][0] = __builtin_amdgcn_mfma_f32_16x16x32_bf16(
                    a, b0, acc[mf][0], 0, 0, 0);
                acc[mf][1] = __builtin_amdgcn_mfma_f32_16x16x32_bf16(
                    a, b1, acc[mf][1], 0, 0, 0);
            }
        }
    }
}

// ---------------------------------------------------------------------------
template <bool FIRST, bool LAST>
__global__ __launch_bounds__(512) void lstm8(
    const float* __restrict__ x,            // [B][1][H][W]
    const short* __restrict__ Bp,           // [3][512][128]
    const float* __restrict__ pxw,          // [3][512]
    const float* __restrict__ pb,           // [512]
    const __hip_bfloat16* __restrict__ hIn, // [B][W][CH] = h(t0-1)
    __hip_bfloat16* __restrict__ hOut,      // [B][W][CH] = h(t0+7)
    const float* __restrict__ cIn,          // [B][W][CH]
    float* __restrict__ cOut,               // [B][W][CH]
    float* __restrict__ pooled,             // [B][CH]
    int t0)
{
    __shared__ alignas(16) short S[ROWS * 128];  // 37376 B, swizzled h slab
    __shared__ float cbuf[512 * 37];             // 75776 B, owner-indexed c
    __shared__ short sibuf[512 * 37];            // 37888 B, owner bf16 sig(i)
    __shared__ float xs[kT][ROWS];               // 4672 B

    const int tid  = threadIdx.x;
    const int lane = tid & 63;
    const int wave = tid >> 6;          // 0..7 = ch-slice
    const int w0   = blockIdx.x * 128;
    const int b    = blockIdx.y;

    const int ncol = lane & 15;
    const int krow = lane >> 4;
    const int ch   = wave * 16 + ncol;  // 0..127

    // per-lane constants: bias + x-channel conv weights
    float wxk[4][3], bia[4];
#pragma unroll
    for (int g = 0; g < 4; ++g) {
        bia[g] = pb[g * 128 + ch];
#pragma unroll
        for (int kx = 0; kx < 3; ++kx)
            wxk[g][kx] = pxw[kx * 512 + g * 128 + ch];
    }

    const float* xb = x + ((size_t)b * kH + t0) * kW;
    const size_t gbase = (size_t)b * kW * kCH;

    // ---- staging: h(t0-1) slab (rows w0-9 .. w0+136) + 8 x rows + c ----
    if (!FIRST) {
        for (int i = tid; i < ROWS * 16; i += 512) {
            int row = i >> 4, col = i & 15;
            int w = w0 - 9 + row;
            short8v v = {0, 0, 0, 0, 0, 0, 0, 0};
            if (w >= 0 && w < kW)
                v = *reinterpret_cast<const short8v*>(
                    reinterpret_cast<const short*>(hIn) +
                    (gbase + (size_t)w * kCH + col * 8));
            *reinterpret_cast<short8v*>(
                S + row * 128 + (col ^ (row & 7)) * 8) = v;
        }
    }
    for (int i = tid; i < kT * ROWS; i += 512) {
        int s8 = i / ROWS, j = i - s8 * ROWS;
        int w = w0 - 9 + j;
        xs[s8][j] = (w >= 0 && w < kW) ? xb[s8 * kW + w] : 0.0f;
    }
    // c: owner-thread cells (cell = mf*4+r, m = mf*16+krow*4+r)
#pragma unroll
    for (int mf = 0; mf < 9; ++mf) {
#pragma unroll
        for (int r = 0; r < 4; ++r) {
            int m = mf * 16 + krow * 4 + r;
            int w = w0 - 8 + m;
            cbuf[tid * 37 + mf * 4 + r] = (!FIRST && w >= 0 && w < kW)
                ? cIn[gbase + (size_t)w * kCH + ch] : 0.0f;
        }
    }
    __syncthreads();

    float psum = 0.0f;

    for (int s = 0; s < kT; ++s) {
        const bool skip = FIRST && (s == 0);

        // ---- phase A: gates i (0), f (1) ----
        {
            float4v acc[9][2];
            gemm_pair<0, 1>(S, Bp, ch, krow, ncol, skip, acc);
#pragma unroll
            for (int mf = 0; mf < 9; ++mf) {
#pragma unroll
                for (int r = 0; r < 4; ++r) {
                    int m = mf * 16 + krow * 4 + r;
                    float xm = xs[s][m], xc = xs[s][m + 1], xp = xs[s][m + 2];
                    float vi = acc[mf][0][r] + bia[0] + xm * wxk[0][0] + xc * wxk[0][1] + xp * wxk[0][2];
                    float vf = acc[mf][1][r] + bia[1] + xm * wxk[1][0] + xc * wxk[1][1] + xp * wxk[1][2];
                    float si = fsig(vi);
                    __hip_bfloat16 sv = __float2bfloat16(si);
                    sibuf[tid * 37 + mf * 4 + r] = *reinterpret_cast<short*>(&sv);
                    cbuf[tid * 37 + mf * 4 + r] *= fsig(vf);
                }
            }
        }

        // ---- phase B: gates g (2), o (3) + state update ----
        {
            float4v acc[9][2];
            gemm_pair<2, 3>(S, Bp, ch, krow, ncol, skip, acc);
            __syncthreads();  // all S reads of this step done
#pragma unroll
            for (int mf = 0; mf < 9; ++mf) {
#pragma unroll
                for (int r = 0; r < 4; ++r) {
                    int m = mf * 16 + krow * 4 + r;
                    int w = w0 - 8 + m;
                    bool inimg = (w >= 0) && (w < kW);
                    bool valid = (m >= s + 1) && (m <= 142 - s) && inimg;
                    float xm = xs[s][m], xc = xs[s][m + 1], xp = xs[s][m + 2];
                    float vg = acc[mf][0][r] + bia[2] + xm * wxk[2][0] + xc * wxk[2][1] + xp * wxk[2][2];
                    float vo = acc[mf][1][r] + bia[3] + xm * wxk[3][0] + xc * wxk[3][1] + xp * wxk[3][2];
                    short sraw = sibuf[tid * 37 + mf * 4 + r];
                    float si = __bfloat162float(
                        *reinterpret_cast<__hip_bfloat16*>(&sraw));
                    float cn = cbuf[tid * 37 + mf * 4 + r] + si * ftanh(vg);
                    cbuf[tid * 37 + mf * 4 + r] = cn;
                    float hn = fsig(vo) * ftanh(cn);
                    if (s < kT - 1) {
                        __hip_bfloat16 hv = __float2bfloat16(valid ? hn : 0.0f);
                        int j2 = m + 1;  // slab row for this w
                        S[j2 * 128 + ((ch >> 3) ^ (j2 & 7)) * 8 + (ch & 7)] =
                            *reinterpret_cast<short*>(&hv);
                    } else if (LAST) {
                        if (valid) psum += hn;
                    } else if (m >= 8 && m < 136) {
                        size_t gi = gbase + (size_t)w * kCH + ch;
                        hOut[gi] = __float2bfloat16(hn);
                        cOut[gi] = cn;
                    }
                }
            }
        }
        __syncthreads();  // S writes visible before next step's GEMM
    }

    if (LAST) {
        psum += __shfl_xor(psum, 16, 64);
        psum += __shfl_xor(psum, 32, 64);
        if (krow == 0) atomicAdd(&pooled[b * kCH + ch], psum);
    }
}

// ---------------------------------------------------------------------------
// Final FC from pooled sums. grid = B, block = 64.
// ---------------------------------------------------------------------------
__global__ __launch_bounds__(64) void fc_final(
    const float* __restrict__ pooled,  // [B][CH] raw sums over W
    const float* __restrict__ fc_w,    // [NC][CH]
    const float* __restrict__ fc_b,    // [NC]
    float* __restrict__ out)           // [B][NC]
{
    int b = blockIdx.x, nc = threadIdx.x;
    if (nc < kNC) {
        float s = 0.0f;
        for (int k = 0; k < kCH; ++k)
            s = fmaf(pooled[b * kCH + k], fc_w[nc * kCH + k], s);
        out[b * kNC + nc] = fc_b[nc] + s * (1.0f / kW);
    }
}

// ---------------------------------------------------------------------------
extern "C" void kernel_launch(void* const* d_in, const int* in_sizes, int n_in,
                              void* d_out, int out_size, void* d_ws, size_t ws_size,
                              hipStream_t stream) {
    const float* x      = (const float*)d_in[0];
    const float* conv_w = (const float*)d_in[1];
    const float* conv_b = (const float*)d_in[2];
    const float* fc_w   = (const float*)d_in[3];
    const float* fc_b   = (const float*)d_in[4];
    float* out = (float*)d_out;

    const size_t stateN = (size_t)kB * kW * kCH;  // 4,194,304
    float* cA           = (float*)d_ws;
    float* cB           = cA + stateN;
    __hip_bfloat16* hA  = (__hip_bfloat16*)(cB + stateN);
    __hip_bfloat16* hB  = hA + stateN;
    short* Bp           = (short*)(hB + stateN);
    float* pxw          = (float*)(Bp + 3 * 512 * 128);
    float* pb           = pxw + 3 * 512;
    float* pooled       = pb + 512;  // [64][128]

    pack_weights<<<768, 256, 0, stream>>>(conv_w, conv_b, Bp, pxw, pb, pooled);

    dim3 grid(kW / 128, kB);
    dim3 block(512);
    // launch k handles t = 8k..8k+7. write(k) = k even ? (hB,cB) : (hA,cA);
    // read(k) = write(k-1).
    lstm8<true, false><<<grid, block, 0, stream>>>(
        x, Bp, pxw, pb, hA, hB, cA, cB, pooled, 0);
    for (int k = 1; k < 15; ++k) {
        __hip_bfloat16* hi = (k & 1) ? hB : hA;
        __hip_bfloat16* ho = (k & 1) ? hA : hB;
        float* ci = (k & 1) ? cB : cA;
        float* co = (k & 1) ? cA : cB;
        lstm8<false, false><<<grid, block, 0, stream>>>(
            x, Bp, pxw, pb, hi, ho, ci, co, pooled, 8 * k);
    }
    // k = 15 (odd): reads (hB,cB); outputs pooled only.
    lstm8<false, true><<<grid, block, 0, stream>>>(
        x, Bp, pxw, pb, hB, hA, cB, cA, pooled, 120);

    fc_final<<<kB, 64, 0, stream>>>(pooled, fc_w, fc_b, out);
}

// Round 9
// 4964.163 us; speedup vs baseline: 1.9173x; 1.1741x over previous
//
#include <hip/hip_runtime.h>
#include <hip/hip_bf16.h>
#include <math.h>

// ConvLSTMClassifier on MI355X — per-step MFMA launches (r2-proven base),
// 8-wave blocks, fused final pooling, bf16 cell state.
// gates[b,w,n] = bias[n] + sum_kx x[b,t,w+kx-1]*pxw[kx,n]
//              + sum_kx sum_ic h[b,w+kx-1,ic]*Bp[kx,n,ic],  n = g*128+ch.
// h, c stored channel-last bf16 [B][W][CH].
// Block: 512 thr / 8 waves; tile M=64 (w rows) x N=512 (all 4 gates x 128 ch).
// Wave = one 16-ch slice, all 4 gates (in-lane epilogue), 4 m-frags.
// A staged in LDS (XOR-swizzled); B gathered per-wave from L2.
// grid = (8 wtiles, 64 b) = 512 blocks (2/CU). 128 launches.

constexpr int kB  = 64;
constexpr int kCH = 128;
constexpr int kH  = 128;
constexpr int kW  = 512;
constexpr int kNC = 10;

typedef __attribute__((ext_vector_type(8))) short short8v;
typedef __attribute__((ext_vector_type(4))) float float4v;

__device__ __forceinline__ float fsig(float v) {
    return 1.0f / (1.0f + __expf(-v));
}
__device__ __forceinline__ float ftanh(float v) {
    float e = __expf(2.0f * v);
    return 1.0f - 2.0f / (e + 1.0f);
}

// ---------------------------------------------------------------------------
// Weight pack: Bp[kx][oc][ic] bf16, pxw[kx][oc] f32, pb[oc] f32.
// Also zeroes the pooled accumulator (ws is poisoned before timing).
// ---------------------------------------------------------------------------
__global__ __launch_bounds__(256) void pack_weights(
    const float* __restrict__ conv_w,  // [512][129][3][3]
    const float* __restrict__ conv_b,  // [512]
    short* __restrict__ Bp,            // [3][512][128]
    float* __restrict__ pxw,           // [3][512]
    float* __restrict__ pb,            // [512]
    float* __restrict__ pooled)        // [64][128]
{
    int idx = blockIdx.x * 256 + threadIdx.x;
    if (idx < 3 * 512 * 128) {
        int ic = idx & 127;
        int oc = (idx >> 7) & 511;
        int kx = idx >> 16;
        float v = conv_w[((oc * 129 + 1 + ic) * 3 + 1) * 3 + kx];
        __hip_bfloat16 hv = __float2bfloat16(v);
        Bp[idx] = *reinterpret_cast<short*>(&hv);
    }
    if (idx < 3 * 512) {
        int oc = idx & 511, kx = idx >> 9;
        pxw[idx] = conv_w[((oc * 129 + 0) * 3 + 1) * 3 + kx];
    }
    if (idx < 512) pb[idx] = conv_b[idx];
    if (idx < kB * kCH) pooled[idx] = 0.0f;
}

// ---------------------------------------------------------------------------
// One LSTM step. grid = (8 wtiles, 64 b), block = 512 (8 waves).
// ---------------------------------------------------------------------------
template <bool FIRST, bool LAST>
__global__ __launch_bounds__(512, 4) void lstm_step(
    const float* __restrict__ x,               // [B][1][H][W]
    const short* __restrict__ Bp,              // [3][512][128]
    const float* __restrict__ pxw,             // [3][512]
    const float* __restrict__ pb,              // [512]
    const __hip_bfloat16* __restrict__ hIn,    // [B][W][CH]
    __hip_bfloat16* __restrict__ hOut,         // [B][W][CH]
    const __hip_bfloat16* __restrict__ cIn,    // [B][W][CH] bf16
    __hip_bfloat16* __restrict__ cOut,         // [B][W][CH] bf16
    float* __restrict__ pooled,                // [B][CH]
    int t)
{
    __shared__ alignas(16) short S[66 * 128];  // h slab rows w0-1..w0+64, swz
    __shared__ float xs[66];

    const int tid  = threadIdx.x;
    const int lane = tid & 63;
    const int wave = tid >> 6;          // 0..7 = 16-ch slice
    const int w0   = blockIdx.x * 64;
    const int b    = blockIdx.y;

    const int ncol = lane & 15;
    const int krow = lane >> 4;
    const int ch   = wave * 16 + ncol;  // 0..127

    const size_t gbase = (size_t)b * kW * kCH;

    // ---- staging: x strip + h slab (once for all 8 waves) ----
    for (int i = tid; i < 66; i += 512) {
        int w = w0 - 1 + i;
        xs[i] = (w >= 0 && w < kW)
              ? x[((size_t)b * kH + t) * kW + w] : 0.0f;
    }
    if (!FIRST) {
        for (int i = tid; i < 66 * 16; i += 512) {
            int row = i >> 4, col = i & 15;
            int w = w0 - 1 + row;
            short8v v = {0, 0, 0, 0, 0, 0, 0, 0};
            if (w >= 0 && w < kW)
                v = *reinterpret_cast<const short8v*>(
                    reinterpret_cast<const short*>(hIn) +
                    (gbase + (size_t)w * kCH + col * 8));
            *reinterpret_cast<short8v*>(
                S + row * 128 + (col ^ (row & 7)) * 8) = v;
        }
    }
    __syncthreads();

    // ---- GEMM: 4 m-frags x 4 gates, K = 3 taps x 128 ch ----
    float4v acc[4][4];
#pragma unroll
    for (int mf = 0; mf < 4; ++mf)
#pragma unroll
        for (int g = 0; g < 4; ++g)
            acc[mf][g] = float4v{0.f, 0.f, 0.f, 0.f};

    if (!FIRST) {
#pragma unroll
        for (int kx = 0; kx < 3; ++kx) {
#pragma unroll
            for (int ks = 0; ks < 4; ++ks) {
                short8v bfr[4];
#pragma unroll
                for (int g = 0; g < 4; ++g)
                    bfr[g] = *reinterpret_cast<const short8v*>(
                        Bp + ((kx * 512 + g * 128 + ch) * 128 +
                              ks * 32 + krow * 8));
#pragma unroll
                for (int mf = 0; mf < 4; ++mf) {
                    int srow = mf * 16 + ncol + kx;
                    int slot = (ks * 4 + krow) ^ (srow & 7);
                    short8v afr = *reinterpret_cast<const short8v*>(
                        S + srow * 128 + slot * 8);
#pragma unroll
                    for (int g = 0; g < 4; ++g)
                        acc[mf][g] = __builtin_amdgcn_mfma_f32_16x16x32_bf16(
                            afr, bfr[g], acc[mf][g], 0, 0, 0);
                }
            }
        }
    }

    // ---- epilogue ----
    float wxk[4][3], bia[4];
#pragma unroll
    for (int g = 0; g < 4; ++g) {
        bia[g] = pb[g * 128 + ch];
#pragma unroll
        for (int kx = 0; kx < 3; ++kx)
            wxk[g][kx] = pxw[kx * 512 + g * 128 + ch];
    }

    float psum = 0.0f;
#pragma unroll
    for (int mf = 0; mf < 4; ++mf) {
#pragma unroll
        for (int r = 0; r < 4; ++r) {
            int m = mf * 16 + krow * 4 + r;
            float xm = xs[m], xc = xs[m + 1], xp = xs[m + 2];
            float v0 = acc[mf][0][r] + bia[0] + xm * wxk[0][0] + xc * wxk[0][1] + xp * wxk[0][2];
            float v1 = acc[mf][1][r] + bia[1] + xm * wxk[1][0] + xc * wxk[1][1] + xp * wxk[1][2];
            float v2 = acc[mf][2][r] + bia[2] + xm * wxk[2][0] + xc * wxk[2][1] + xp * wxk[2][2];
            float v3 = acc[mf][3][r] + bia[3] + xm * wxk[3][0] + xc * wxk[3][1] + xp * wxk[3][2];
            size_t gi = gbase + (size_t)(w0 + m) * kCH + ch;
            float cprev = FIRST ? 0.0f : __bfloat162float(cIn[gi]);
            float si = fsig(v0);
            float sf = fsig(v1);
            float tg = ftanh(v2);
            float so = fsig(v3);
            float cn = sf * cprev + si * tg;
            float hn = so * ftanh(cn);
            if (LAST) {
                psum += hn;
            } else {
                cOut[gi] = __float2bfloat16(cn);
                hOut[gi] = __float2bfloat16(hn);
            }
        }
    }

    if (LAST) {
        // lanes with same ncol (ch) across krow: xor 16, 32
        psum += __shfl_xor(psum, 16, 64);
        psum += __shfl_xor(psum, 32, 64);
        if (krow == 0) atomicAdd(&pooled[b * kCH + ch], psum);
    }
}

// ---------------------------------------------------------------------------
// Final FC from pooled sums. grid = B, block = 64.
// ---------------------------------------------------------------------------
__global__ __launch_bounds__(64) void fc_final(
    const float* __restrict__ pooled,  // [B][CH] raw sums over W
    const float* __restrict__ fc_w,    // [NC][CH]
    const float* __restrict__ fc_b,    // [NC]
    float* __restrict__ out)           // [B][NC]
{
    int b = blockIdx.x, nc = threadIdx.x;
    if (nc < kNC) {
        float s = 0.0f;
        for (int k = 0; k < kCH; ++k)
            s = fmaf(pooled[b * kCH + k], fc_w[nc * kCH + k], s);
        out[b * kNC + nc] = fc_b[nc] + s * (1.0f / kW);
    }
}

// ---------------------------------------------------------------------------
extern "C" void kernel_launch(void* const* d_in, const int* in_sizes, int n_in,
                              void* d_out, int out_size, void* d_ws, size_t ws_size,
                              hipStream_t stream) {
    const float* x      = (const float*)d_in[0];
    const float* conv_w = (const float*)d_in[1];
    const float* conv_b = (const float*)d_in[2];
    const float* fc_w   = (const float*)d_in[3];
    const float* fc_b   = (const float*)d_in[4];
    float* out = (float*)d_out;

    const size_t stateN = (size_t)kB * kW * kCH;  // 4,194,304
    __hip_bfloat16* cA  = (__hip_bfloat16*)d_ws;
    __hip_bfloat16* cB  = cA + stateN;
    __hip_bfloat16* hA  = cB + stateN;
    __hip_bfloat16* hB  = hA + stateN;
    short* Bp           = (short*)(hB + stateN);
    float* pxw          = (float*)(Bp + 3 * 512 * 128);
    float* pb           = pxw + 3 * 512;
    float* pooled       = pb + 512;  // [64][128]

    pack_weights<<<768, 256, 0, stream>>>(conv_w, conv_b, Bp, pxw, pb, pooled);

    dim3 grid(kW / 64, kB);
    dim3 block(512);
    // write(t) = t even ? (hB,cB) : (hA,cA); read(t) = write(t-1).
    lstm_step<true, false><<<grid, block, 0, stream>>>(
        x, Bp, pxw, pb, hA, hB, cA, cB, pooled, 0);
    for (int t = 1; t < kH - 1; ++t) {
        const __hip_bfloat16* hi = (t & 1) ? hB : hA;
        __hip_bfloat16*       ho = (t & 1) ? hA : hB;
        const __hip_bfloat16* ci = (t & 1) ? cB : cA;
        __hip_bfloat16*       co = (t & 1) ? cA : cB;
        lstm_step<false, false><<<grid, block, 0, stream>>>(
            x, Bp, pxw, pb, hi, ho, ci, co, pooled, t);
    }
    // t = 127 (odd): reads write(126) = (hB,cB); outputs pooled only.
    lstm_step<false, true><<<grid, block, 0, stream>>>(
        x, Bp, pxw, pb, hB, hA, cB, cA, pooled, 127);

    fc_final<<<kB, 64, 0, stream>>>(pooled, fc_w, fc_b, out);
}

// Round 10
// 4935.777 us; speedup vs baseline: 1.9283x; 1.0058x over previous
//
#include <hip/hip_runtime.h>
#include <hip/hip_bf16.h>
#include <math.h>

// ConvLSTMClassifier on MI355X — per-step MFMA launches, packed hc state.
// gates[b,w,n] = bias[n] + sum_kx x[b,t,w+kx-1]*pxw[kx,n]
//              + sum_kx sum_ic h[b,w+kx-1,ic]*Bp[kx,n,ic],  n = g*128+ch.
// State: hc[b][w][ch] uint32 = h(bf16, lo16) | c(bf16, hi16). Full-sector
// writes (16 lanes x 4B = 64B), h+c share cache lines on read.
// Block: 512 thr / 8 waves; tile M=64 (w rows) x N=512 (4 gates x 128 ch).
// Wave = one 16-ch slice, all 4 gates; 4 m-frags. acc 64 AGPR + 64 VGPR
// -> 4 waves/SIMD (unified regfile budget), the proven r9 config.
// grid = (8 wtiles, 64 b) = 512 blocks (2/CU). 128 launches + fc.

constexpr int kB  = 64;
constexpr int kCH = 128;
constexpr int kH  = 128;
constexpr int kW  = 512;
constexpr int kNC = 10;

typedef __attribute__((ext_vector_type(8))) short short8v;
typedef __attribute__((ext_vector_type(4))) float float4v;

__device__ __forceinline__ float fsig(float v) {
    return 1.0f / (1.0f + __expf(-v));
}
__device__ __forceinline__ float ftanh(float v) {
    float e = __expf(2.0f * v);
    return 1.0f - 2.0f / (e + 1.0f);
}

// ---------------------------------------------------------------------------
// Weight pack: Bp[kx][oc][ic] bf16, pxw[kx][oc] f32, pb[oc] f32.
// Also zeroes the pooled accumulator (ws is poisoned before timing).
// ---------------------------------------------------------------------------
__global__ __launch_bounds__(256) void pack_weights(
    const float* __restrict__ conv_w,  // [512][129][3][3]
    const float* __restrict__ conv_b,  // [512]
    short* __restrict__ Bp,            // [3][512][128]
    float* __restrict__ pxw,           // [3][512]
    float* __restrict__ pb,            // [512]
    float* __restrict__ pooled)        // [64][128]
{
    int idx = blockIdx.x * 256 + threadIdx.x;
    if (idx < 3 * 512 * 128) {
        int ic = idx & 127;
        int oc = (idx >> 7) & 511;
        int kx = idx >> 16;
        float v = conv_w[((oc * 129 + 1 + ic) * 3 + 1) * 3 + kx];
        __hip_bfloat16 hv = __float2bfloat16(v);
        Bp[idx] = *reinterpret_cast<short*>(&hv);
    }
    if (idx < 3 * 512) {
        int oc = idx & 511, kx = idx >> 9;
        pxw[idx] = conv_w[((oc * 129 + 0) * 3 + 1) * 3 + kx];
    }
    if (idx < 512) pb[idx] = conv_b[idx];
    if (idx < kB * kCH) pooled[idx] = 0.0f;
}

// ---------------------------------------------------------------------------
// One LSTM step. grid = (8 wtiles, 64 b), block = 512 (8 waves).
// ---------------------------------------------------------------------------
template <bool FIRST, bool LAST>
__global__ __launch_bounds__(512, 4) void lstm_step(
    const float* __restrict__ x,            // [B][1][H][W]
    const short* __restrict__ Bp,           // [3][512][128]
    const float* __restrict__ pxw,          // [3][512]
    const float* __restrict__ pb,           // [512]
    const unsigned int* __restrict__ hcIn,  // [B][W][CH] packed h|c
    unsigned int* __restrict__ hcOut,       // [B][W][CH] packed h|c
    float* __restrict__ pooled,             // [B][CH]
    int t)
{
    __shared__ alignas(16) short S[66 * 128];  // h slab rows w0-1..w0+64, swz
    __shared__ float xs[66];

    const int tid  = threadIdx.x;
    const int lane = tid & 63;
    const int wave = tid >> 6;          // 0..7 = 16-ch slice
    const int w0   = blockIdx.x * 64;
    const int b    = blockIdx.y;

    const int ncol = lane & 15;
    const int krow = lane >> 4;
    const int ch   = wave * 16 + ncol;  // 0..127

    const size_t gbase = (size_t)b * kW * kCH;

    // ---- staging: x strip + h slab (extract lo16 of packed hc) ----
    for (int i = tid; i < 66; i += 512) {
        int w = w0 - 1 + i;
        xs[i] = (w >= 0 && w < kW)
              ? x[((size_t)b * kH + t) * kW + w] : 0.0f;
    }
    if (!FIRST) {
        for (int i = tid; i < 66 * 16; i += 512) {
            int row = i >> 4, col = i & 15;
            int w = w0 - 1 + row;
            short8v v = {0, 0, 0, 0, 0, 0, 0, 0};
            if (w >= 0 && w < kW) {
                const uint4* p = reinterpret_cast<const uint4*>(
                    hcIn + gbase + (size_t)w * kCH + col * 8);
                uint4 a = p[0];
                uint4 d = p[1];
                v[0] = (short)(a.x & 0xffff);
                v[1] = (short)(a.y & 0xffff);
                v[2] = (short)(a.z & 0xffff);
                v[3] = (short)(a.w & 0xffff);
                v[4] = (short)(d.x & 0xffff);
                v[5] = (short)(d.y & 0xffff);
                v[6] = (short)(d.z & 0xffff);
                v[7] = (short)(d.w & 0xffff);
            }
            *reinterpret_cast<short8v*>(
                S + row * 128 + (col ^ (row & 7)) * 8) = v;
        }
    }
    __syncthreads();

    // ---- GEMM: 4 m-frags x 4 gates, K = 3 taps x 128 ch ----
    float4v acc[4][4];
#pragma unroll
    for (int mf = 0; mf < 4; ++mf)
#pragma unroll
        for (int g = 0; g < 4; ++g)
            acc[mf][g] = float4v{0.f, 0.f, 0.f, 0.f};

    if (!FIRST) {
#pragma unroll
        for (int kx = 0; kx < 3; ++kx) {
#pragma unroll
            for (int ks = 0; ks < 4; ++ks) {
                short8v bfr[4];
#pragma unroll
                for (int g = 0; g < 4; ++g)
                    bfr[g] = *reinterpret_cast<const short8v*>(
                        Bp + ((kx * 512 + g * 128 + ch) * 128 +
                              ks * 32 + krow * 8));
#pragma unroll
                for (int mf = 0; mf < 4; ++mf) {
                    int srow = mf * 16 + ncol + kx;
                    int slot = (ks * 4 + krow) ^ (srow & 7);
                    short8v afr = *reinterpret_cast<const short8v*>(
                        S + srow * 128 + slot * 8);
#pragma unroll
                    for (int g = 0; g < 4; ++g)
                        acc[mf][g] = __builtin_amdgcn_mfma_f32_16x16x32_bf16(
                            afr, bfr[g], acc[mf][g], 0, 0, 0);
                }
            }
        }
    }

    // ---- epilogue (constants loaded after GEMM to limit live range) ----
    float wxk[4][3], bia[4];
#pragma unroll
    for (int g = 0; g < 4; ++g) {
        bia[g] = pb[g * 128 + ch];
#pragma unroll
        for (int kx = 0; kx < 3; ++kx)
            wxk[g][kx] = pxw[kx * 512 + g * 128 + ch];
    }

    float psum = 0.0f;
#pragma unroll
    for (int mf = 0; mf < 4; ++mf) {
        // hoist this mf's 4 packed-state loads ahead of the gate math
        unsigned int cu[4];
        if (!FIRST) {
#pragma unroll
            for (int r = 0; r < 4; ++r) {
                int m = mf * 16 + krow * 4 + r;
                cu[r] = hcIn[gbase + (size_t)(w0 + m) * kCH + ch];
            }
        }
#pragma unroll
        for (int r = 0; r < 4; ++r) {
            int m = mf * 16 + krow * 4 + r;
            float xm = xs[m], xc = xs[m + 1], xp = xs[m + 2];
            float v0 = acc[mf][0][r] + bia[0] + xm * wxk[0][0] + xc * wxk[0][1] + xp * wxk[0][2];
            float v1 = acc[mf][1][r] + bia[1] + xm * wxk[1][0] + xc * wxk[1][1] + xp * wxk[1][2];
            float v2 = acc[mf][2][r] + bia[2] + xm * wxk[2][0] + xc * wxk[2][1] + xp * wxk[2][2];
            float v3 = acc[mf][3][r] + bia[3] + xm * wxk[3][0] + xc * wxk[3][1] + xp * wxk[3][2];
            float cprev = 0.0f;
            if (!FIRST) {
                unsigned int cb = cu[r] & 0xffff0000u;  // c bf16 bits -> f32
                cprev = *reinterpret_cast<float*>(&cb);
            }
            float si = fsig(v0);
            float sf = fsig(v1);
            float tg = ftanh(v2);
            float so = fsig(v3);
            float cn = sf * cprev + si * tg;
            float hn = so * ftanh(cn);
            if (LAST) {
                psum += hn;
            } else {
                __hip_bfloat16 hb = __float2bfloat16(hn);
                __hip_bfloat16 cb2 = __float2bfloat16(cn);
                unsigned int packed =
                    (unsigned int)*reinterpret_cast<unsigned short*>(&hb) |
                    ((unsigned int)*reinterpret_cast<unsigned short*>(&cb2) << 16);
                hcOut[gbase + (size_t)(w0 + m) * kCH + ch] = packed;
            }
        }
    }

    if (LAST) {
        // lanes with same ch across krow: xor 16, 32
        psum += __shfl_xor(psum, 16, 64);
        psum += __shfl_xor(psum, 32, 64);
        if (krow == 0) atomicAdd(&pooled[b * kCH + ch], psum);
    }
}

// ---------------------------------------------------------------------------
// Final FC from pooled sums. grid = B, block = 64.
// ---------------------------------------------------------------------------
__global__ __launch_bounds__(64) void fc_final(
    const float* __restrict__ pooled,  // [B][CH] raw sums over W
    const float* __restrict__ fc_w,    // [NC][CH]
    const float* __restrict__ fc_b,    // [NC]
    float* __restrict__ out)           // [B][NC]
{
    int b = blockIdx.x, nc = threadIdx.x;
    if (nc < kNC) {
        float s = 0.0f;
        for (int k = 0; k < kCH; ++k)
            s = fmaf(pooled[b * kCH + k], fc_w[nc * kCH + k], s);
        out[b * kNC + nc] = fc_b[nc] + s * (1.0f / kW);
    }
}

// ---------------------------------------------------------------------------
extern "C" void kernel_launch(void* const* d_in, const int* in_sizes, int n_in,
                              void* d_out, int out_size, void* d_ws, size_t ws_size,
                              hipStream_t stream) {
    const float* x      = (const float*)d_in[0];
    const float* conv_w = (const float*)d_in[1];
    const float* conv_b = (const float*)d_in[2];
    const float* fc_w   = (const float*)d_in[3];
    const float* fc_b   = (const float*)d_in[4];
    float* out = (float*)d_out;

    const size_t stateN = (size_t)kB * kW * kCH;  // 4,194,304
    unsigned int* hcA   = (unsigned int*)d_ws;
    unsigned int* hcB   = hcA + stateN;
    short* Bp           = (short*)(hcB + stateN);
    float* pxw          = (float*)(Bp + 3 * 512 * 128);
    float* pb           = pxw + 3 * 512;
    float* pooled       = pb + 512;  // [64][128]

    pack_weights<<<768, 256, 0, stream>>>(conv_w, conv_b, Bp, pxw, pb, pooled);

    dim3 grid(kW / 64, kB);
    dim3 block(512);
    // write(t) = t even ? hcB : hcA; read(t) = write(t-1).
    lstm_step<true, false><<<grid, block, 0, stream>>>(
        x, Bp, pxw, pb, hcA, hcB, pooled, 0);
    for (int t = 1; t < kH - 1; ++t) {
        const unsigned int* hi = (t & 1) ? hcB : hcA;
        unsigned int*       ho = (t & 1) ? hcA : hcB;
        lstm_step<false, false><<<grid, block, 0, stream>>>(
            x, Bp, pxw, pb, hi, ho, pooled, t);
    }
    // t = 127 (odd): reads write(126) = hcB; outputs pooled only.
    lstm_step<false, true><<<grid, block, 0, stream>>>(
        x, Bp, pxw, pb, hcB, hcA, pooled, 127);

    fc_final<<<kB, 64, 0, stream>>>(pooled, fc_w, fc_b, out);
}